// Round 11
// baseline (8307.608 us; speedup 1.0000x reference)
//
#include <hip/hip_runtime.h>
#include <math.h>

#define SS 512
#define BB 64
#define EE 256
#define HH 512
#define NT 9
#define NWG 256

// ws layout (float32 elements):
//  hs   : SS*BB*HH at 0        (hs[t] = h_t)
//  em   : SS*BB*NT at EM_OFF
//  num  : 64 at NUM_OFF
//  norm : 64 at NORM_OFF
//  flags: SS*8*32 u32 at FLAG_OFF   (flag per (t, bg, slice); 128B line per (t,bg))
#define HS_ELEMS ((size_t)SS * BB * HH)
#define EM_OFF   HS_ELEMS
#define NUM_OFF  (EM_OFF + (size_t)SS * BB * NT)
#define NORM_OFF (NUM_OFF + 64)
#define FLAG_OFF (NORM_OFF + 64)
#define FLAG_U32S ((size_t)SS * 8 * 32)

// dynamic LDS layout (floats) -- h_l is GONE (h read direct from LLC)
#define L_WHH 0            // 64 rows x 512       = 32768 floats (128 KB)
#define L_GSM 32768        // 64 x 9              = 576
#define L_CS  33344        // 16 x 8              = 128
#define L_TOT 33472        // 133888 bytes

__global__ __launch_bounds__(256) void init_flags(float* __restrict__ ws) {
    unsigned* f = (unsigned*)(ws + FLAG_OFF);
    size_t idx = (size_t)blockIdx.x * 256 + threadIdx.x;
    if (idx < FLAG_U32S) f[idx] = 0u;
}

// Persistent LSTM: 256 WGs x 512 threads, one step per flag-barrier round.
// WG (slice = wg&31, bg = wg>>5): units slice*16..+16, batches bg*8..+8.
// Wave w: local gate-rows w*8..w*8+7. Lane L: b_l = L&7, kc = L>>3.
// Whh in LDS (staged once). DELTA vs R10 (6.15ms): h is read DIRECTLY from
// LLC in the hh loop (relaxed-agent dwordx2 loads) -- no h_l staging, no
// staging syncthreads, no conflicted h ds_reads. LDS pipe now carries only
// the broadcast Whh reads (128/wave/step) + gsm. 2 syncthreads/step.
__global__ __launch_bounds__(512) void lstm_persistent(
    const float* __restrict__ Whh, const float* __restrict__ Wih,
    const float* __restrict__ bih, const float* __restrict__ bhh,
    const float* __restrict__ emb, const int* __restrict__ x,
    float* __restrict__ ws)
{
    const int wg    = blockIdx.x;
    const int slice = wg & 31;
    const int bg    = wg >> 5;
    const int tid   = threadIdx.x;
    const int w     = tid >> 6;
    const int L     = tid & 63;
    const int b_l   = L & 7;
    const int kc    = L >> 3;
    const int b     = bg * 8 + b_l;

    float* hs = ws;
    unsigned* flags = (unsigned*)(ws + FLAG_OFF);

    extern __shared__ float smem[];
    float* whh_l = smem + L_WHH;   // [l][512], l = local gate-row
    float* gsm   = smem + L_GSM;   // [64][9]
    float* cs_l  = smem + L_CS;    // [u][8]

    int grow[8];
#pragma unroll
    for (int r = 0; r < 8; r++) {
        int l = w * 8 + r;
        grow[r] = (l >> 4) * HH + slice * 16 + (l & 15);
    }

    // ---- stage Whh slice (64 rows x 512) into LDS, coalesced ----
    for (int j = 0; j < 64; j++) {
        int idx = j * 512 + tid;          // l*512 + k
        int l = idx >> 9;
        int k = idx & 511;
        int gr = (l >> 4) * HH + slice * 16 + (l & 15);
        whh_l[idx] = Whh[(size_t)gr * HH + k];
    }

    // bias preload (activation threads only)
    float bs0 = 0.f, bs1 = 0.f, bs2 = 0.f, bs3 = 0.f;
    if (tid < 128) {
        const int u  = tid & 15;
        const int bb = tid >> 4;
        const int gu = slice * 16 + u;
        bs0 = bih[0 * HH + gu] + bhh[0 * HH + gu];
        bs1 = bih[1 * HH + gu] + bhh[1 * HH + gu];
        bs2 = bih[2 * HH + gu] + bhh[2 * HH + gu];
        bs3 = bih[3 * HH + gu] + bhh[3 * HH + gu];
        cs_l[u * 8 + bb] = 0.0f;
    }

    // ih-gates for t=0
    float acc_ih[8];
    {
        const int xv = x[0 * BB + b];
        const float* erow = emb + (size_t)xv * EE;
#pragma unroll
        for (int r = 0; r < 8; r++) acc_ih[r] = 0.0f;
        for (int c = 0; c < 8; c++) {
            const int k0 = c * 32 + kc * 4;
            float4 e4 = *(const float4*)(erow + k0);
            e4.x *= 16.0f; e4.y *= 16.0f; e4.z *= 16.0f; e4.w *= 16.0f;
#pragma unroll
            for (int r = 0; r < 8; r++) {
                float4 w4 = *(const float4*)(Wih + (size_t)grow[r] * EE + k0);
                acc_ih[r] += w4.x * e4.x + w4.y * e4.y + w4.z * e4.z + w4.w * e4.w;
            }
        }
    }
    __syncthreads();   // whh_l / cs_l ready

    const float* wbase = whh_l + (size_t)(w * 8) * 512;

    for (int t = 0; t < SS; t++) {
        float acc[8];
#pragma unroll
        for (int r = 0; r < 8; r++) acc[r] = acc_ih[r];

        if (t > 0) {
            // ---- per-wave poll of the 32-flag line for (t-1, bg) ----
            const unsigned* fl = flags + ((size_t)(t - 1) * 8 + bg) * 32;
            for (;;) {
                unsigned v = 1u;
                if (L < 32)
                    v = __hip_atomic_load(&fl[L], __ATOMIC_RELAXED,
                                          __HIP_MEMORY_SCOPE_AGENT);
                if (__all(v != 0u)) break;
            }

            // ---- hh gates: h_{t-1} DIRECT from LLC, Whh from LDS ----
            const float* hsrc = hs + (size_t)(t - 1) * BB * HH + (size_t)b * HH;
            for (int c = 0; c < 16; c++) {
                const int k0 = c * 32 + kc * 4;
                unsigned long long u0 = __hip_atomic_load(
                    (const unsigned long long*)(hsrc + k0),
                    __ATOMIC_RELAXED, __HIP_MEMORY_SCOPE_AGENT);
                unsigned long long u1 = __hip_atomic_load(
                    (const unsigned long long*)(hsrc + k0 + 2),
                    __ATOMIC_RELAXED, __HIP_MEMORY_SCOPE_AGENT);
                float hx = __uint_as_float((unsigned)u0);
                float hy = __uint_as_float((unsigned)(u0 >> 32));
                float hz = __uint_as_float((unsigned)u1);
                float hw = __uint_as_float((unsigned)(u1 >> 32));
#pragma unroll
                for (int r = 0; r < 8; r++) {
                    float4 w4 = *(const float4*)(wbase + r * 512 + k0);
                    acc[r] += w4.x * hx + w4.y * hy + w4.z * hz + w4.w * hw;
                }
            }
        }

        // ---- reduce over 8 kc-lanes ----
#pragma unroll
        for (int r = 0; r < 8; r++) {
            acc[r] += __shfl_xor(acc[r], 8, 64);
            acc[r] += __shfl_xor(acc[r], 16, 64);
            acc[r] += __shfl_xor(acc[r], 32, 64);
        }
        float myv = acc[0];
#pragma unroll
        for (int r = 1; r < 8; r++) if (kc == r) myv = acc[r];
        gsm[(w * 8 + kc) * 9 + b_l] = myv;
        __syncthreads();

        // ---- activations + state update + h_t store (relaxed agent) ----
        if (tid < 128) {
            const int u  = tid & 15;
            const int bb = tid >> 4;
            const int gu = slice * 16 + u;
            float gi = gsm[(0 * 16 + u) * 9 + bb] + bs0;
            float gf = gsm[(1 * 16 + u) * 9 + bb] + bs1;
            float gg = gsm[(2 * 16 + u) * 9 + bb] + bs2;
            float go = gsm[(3 * 16 + u) * 9 + bb] + bs3;
            float i_ = 1.0f / (1.0f + expf(-gi));
            float f_ = 1.0f / (1.0f + expf(-gf));
            float o_ = 1.0f / (1.0f + expf(-go));
            const int gb = bg * 8 + bb;
            float cn = f_ * cs_l[u * 8 + bb] + i_ * tanhf(gg);
            float hn = o_ * tanhf(cn);
            cs_l[u * 8 + bb] = cn;
            __hip_atomic_store(&hs[(size_t)t * BB * HH + (size_t)gb * HH + gu],
                               hn, __ATOMIC_RELAXED, __HIP_MEMORY_SCOPE_AGENT);
        }
        __syncthreads();   // each wave drains vmcnt before barrier: h at LLC

        if (t + 1 < SS) {
            // ---- publish our slice's flag (data already at LLC) ----
            if (tid == 0)
                __hip_atomic_store(&flags[((size_t)t * 8 + bg) * 32 + slice], 1u,
                                   __ATOMIC_RELAXED, __HIP_MEMORY_SCOPE_AGENT);

            // ---- ih(t+1) ----
            const int xv = x[(t + 1) * BB + b];
            const float* erow = emb + (size_t)xv * EE;
#pragma unroll
            for (int r = 0; r < 8; r++) acc_ih[r] = 0.0f;
            for (int c = 0; c < 8; c++) {
                const int k0 = c * 32 + kc * 4;
                float4 e4 = *(const float4*)(erow + k0);
                e4.x *= 16.0f; e4.y *= 16.0f; e4.z *= 16.0f; e4.w *= 16.0f;
#pragma unroll
                for (int r = 0; r < 8; r++) {
                    float4 w4 = *(const float4*)(Wih + (size_t)grow[r] * EE + k0);
                    acc_ih[r] += w4.x * e4.x + w4.y * e4.y + w4.z * e4.z + w4.w * e4.w;
                }
            }
        }
    }
}

// one wave per (t,b): logits = h @ W_out^T + b_out, then log_softmax
__global__ __launch_bounds__(256) void emis_kernel(
    const float* __restrict__ Wout, const float* __restrict__ bout,
    float* __restrict__ ws)
{
    int wid = blockIdx.x * 4 + (threadIdx.x >> 6);  // t*64 + b
    int L   = threadIdx.x & 63;
    const float* h = ws + (size_t)wid * HH;
    float hv[8];
#pragma unroll
    for (int i = 0; i < 8; i++) hv[i] = h[i * 64 + L];
    float acc[9];
#pragma unroll
    for (int tg = 0; tg < 9; tg++) acc[tg] = 0.0f;
    for (int i = 0; i < 8; i++) {
#pragma unroll
        for (int tg = 0; tg < 9; tg++)
            acc[tg] += Wout[tg * HH + i * 64 + L] * hv[i];
    }
#pragma unroll
    for (int tg = 0; tg < 9; tg++) {
        acc[tg] += __shfl_xor(acc[tg], 1, 64);
        acc[tg] += __shfl_xor(acc[tg], 2, 64);
        acc[tg] += __shfl_xor(acc[tg], 4, 64);
        acc[tg] += __shfl_xor(acc[tg], 8, 64);
        acc[tg] += __shfl_xor(acc[tg], 16, 64);
        acc[tg] += __shfl_xor(acc[tg], 32, 64);
    }
    float lg[9];
#pragma unroll
    for (int tg = 0; tg < 9; tg++) lg[tg] = acc[tg] + bout[tg];
    float m = lg[0];
#pragma unroll
    for (int tg = 1; tg < 9; tg++) m = fmaxf(m, lg[tg]);
    float ssum = 0.0f;
#pragma unroll
    for (int tg = 0; tg < 9; tg++) ssum += expf(lg[tg] - m);
    float lse = m + logf(ssum);
    float myo = lg[0] - lse;
#pragma unroll
    for (int tg = 1; tg < 9; tg++) if (L == tg) myo = lg[tg] - lse;
    if (L < 9) ws[EM_OFF + (size_t)wid * 9 + L] = myo;
}

// merged CRF: blocks 0..7 numerator, 8..15 forward(logZ), 16..23 viterbi
__global__ __launch_bounds__(512) void crf_all(
    const int* __restrict__ x, const int* __restrict__ bio,
    const float* __restrict__ start_t, const float* __restrict__ end_t,
    const float* __restrict__ trans, float* __restrict__ ws,
    float* __restrict__ out)
{
    const float* em = ws + EM_OFF;
    const int role  = blockIdx.x >> 3;
    const int local = blockIdx.x & 7;
    const int tid   = threadIdx.x;

    __shared__ float sc[9][8];
    __shared__ unsigned char hist[SS - 1][8][9];

    if (role == 0) {
        int b = local * 8 + (tid >> 6);
        int L = tid & 63;
        float sum = 0.0f;
        int cntm = 0;
#pragma unroll
        for (int j = 0; j < 8; j++) {
            int s = j * 64 + L;
            int tg = bio[s * BB + b];
            bool mk = (x[s * BB + b] != 0);
            cntm += mk ? 1 : 0;
            if (s == 0) {
                sum += start_t[tg] + em[(size_t)b * 9 + tg];
            } else if (mk) {
                int tp = bio[(s - 1) * BB + b];
                sum += em[((size_t)s * BB + b) * 9 + tg] + trans[tp * 9 + tg];
            }
        }
#pragma unroll
        for (int d = 1; d < 64; d <<= 1) {
            sum += __shfl_xor(sum, d, 64);
            cntm += __shfl_xor(cntm, d, 64);
        }
        if (L == 0) {
            int se = cntm - 1;
            sum += end_t[bio[se * BB + b]];
            ws[NUM_OFF + b] = sum;
        }
        return;
    }

    const int b_l = tid & 7;
    const int j   = tid >> 3;          // active j < 9
    const int b   = local * 8 + b_l;
    float tc[9];
    if (j < 9) {
#pragma unroll
        for (int i = 0; i < 9; i++) tc[i] = trans[i * 9 + j];
        sc[j][b_l] = start_t[j] + em[(size_t)b * 9 + j];
    }
    __syncthreads();

    if (role == 1) {
        for (int s = 1; s < SS; s++) {
            float nv = 0.0f;
            if (j < 9) {
                float sv[9];
                float m = -3.4e38f;
#pragma unroll
                for (int i = 0; i < 9; i++) {
                    sv[i] = sc[i][b_l] + tc[i];
                    m = fmaxf(m, sv[i]);
                }
                float ssum = 0.0f;
#pragma unroll
                for (int i = 0; i < 9; i++) ssum += expf(sv[i] - m);
                nv = m + logf(ssum) + em[((size_t)s * BB + b) * 9 + j];
            }
            bool mk = (x[s * BB + b] != 0);
            __syncthreads();
            if (j < 9 && mk) sc[j][b_l] = nv;
            __syncthreads();
        }
        if (j == 0) {
            float m = -3.4e38f;
#pragma unroll
            for (int i = 0; i < 9; i++) m = fmaxf(m, sc[i][b_l] + end_t[i]);
            float ssum = 0.0f;
#pragma unroll
            for (int i = 0; i < 9; i++) ssum += expf(sc[i][b_l] + end_t[i] - m);
            ws[NORM_OFF + b] = m + logf(ssum);
        }
    } else {
        for (int s = 1; s < SS; s++) {
            float nv = 0.0f;
            if (j < 9) {
                float best = sc[0][b_l] + tc[0];
                int bi = 0;
#pragma unroll
                for (int i = 1; i < 9; i++) {
                    float v = sc[i][b_l] + tc[i];
                    if (v > best) { best = v; bi = i; }  // first-max = jnp.argmax
                }
                hist[s - 1][b_l][j] = (unsigned char)bi;
                nv = best + em[((size_t)s * BB + b) * 9 + j];
            }
            __syncthreads();
            if (j < 9) sc[j][b_l] = nv;
            __syncthreads();
        }
        if (tid < 8) {
            int bl = tid;
            int gb = local * 8 + bl;
            float best = sc[0][bl] + end_t[0];
            int cur = 0;
#pragma unroll
            for (int i = 1; i < 9; i++) {
                float v = sc[i][bl] + end_t[i];
                if (v > best) { best = v; cur = i; }
            }
            out[1 + (size_t)(SS - 1) * BB + gb] = (float)cur;
            for (int s = SS - 2; s >= 0; s--) {
                cur = hist[s][bl][cur];
                out[1 + (size_t)s * BB + gb] = (float)cur;
            }
        }
    }
}

__global__ __launch_bounds__(64) void final_llh(const float* __restrict__ ws,
                                               float* __restrict__ out)
{
    int L = threadIdx.x;
    float v = ws[NUM_OFF + L] - ws[NORM_OFF + L];
    v += __shfl_xor(v, 1, 64);
    v += __shfl_xor(v, 2, 64);
    v += __shfl_xor(v, 4, 64);
    v += __shfl_xor(v, 8, 64);
    v += __shfl_xor(v, 16, 64);
    v += __shfl_xor(v, 32, 64);
    if (L == 0) out[0] = -v;
}

extern "C" void kernel_launch(void* const* d_in, const int* in_sizes, int n_in,
                              void* d_out, int out_size, void* d_ws, size_t ws_size,
                              hipStream_t stream) {
    const int*   x       = (const int*)d_in[0];
    const int*   bio     = (const int*)d_in[1];
    const float* emb     = (const float*)d_in[2];
    const float* W_ih    = (const float*)d_in[3];
    const float* W_hh    = (const float*)d_in[4];
    const float* b_ih    = (const float*)d_in[5];
    const float* b_hh    = (const float*)d_in[6];
    const float* W_out   = (const float*)d_in[7];
    const float* b_out   = (const float*)d_in[8];
    const float* start_t = (const float*)d_in[9];
    const float* end_t   = (const float*)d_in[10];
    const float* trans   = (const float*)d_in[11];
    float* out = (float*)d_out;
    float* ws  = (float*)d_ws;

    const size_t dyn_lds = (size_t)L_TOT * sizeof(float);   // 133888 B
    hipFuncSetAttribute((const void*)lstm_persistent,
                        hipFuncAttributeMaxDynamicSharedMemorySize,
                        (int)dyn_lds);

    init_flags<<<512, 256, 0, stream>>>(ws);
    lstm_persistent<<<NWG, 512, dyn_lds, stream>>>(W_hh, W_ih, b_ih, b_hh, emb, x, ws);
    emis_kernel<<<SS * BB / 4, 256, 0, stream>>>(W_out, b_out, ws);
    crf_all<<<24, 512, 0, stream>>>(x, bio, start_t, end_t, trans, ws, out);
    final_llh<<<1, 64, 0, stream>>>(ws, out);
}

// Round 12
// 7309.833 us; speedup vs baseline: 1.1365x; 1.1365x over previous
//
#include <hip/hip_runtime.h>
#include <math.h>

#define SS 512
#define BB 64
#define EE 256
#define HH 512
#define NT 9
#define NWG 256

// ws layout (float32 elements):
//  hs   : SS*BB*HH at 0        (hs[t] = h_t, [t][b][u])
//  em   : SS*BB*NT at EM_OFF
//  num  : 64 at NUM_OFF
//  norm : 64 at NORM_OFF
//  flags: SS*4*64 u32 at FLAG_OFF   (flag per (t, bgr, rg); 256B line per (t,bgr))
#define HS_ELEMS ((size_t)SS * BB * HH)
#define EM_OFF   HS_ELEMS
#define NUM_OFF  (EM_OFF + (size_t)SS * BB * NT)
#define NORM_OFF (NUM_OFF + 64)
#define FLAG_OFF (NORM_OFF + 64)
#define FLAG_U32S ((size_t)SS * 4 * 64)

// dynamic LDS layout (floats)
#define L_WHH 0            // 32 rows x 512            = 16384 (64 KB)
#define L_H   16384        // 16 x 520                 = 8320
#define L_GSM 24704        // 32 x 17                  = 544
#define L_CS  25248        // 8u x 16b                 = 128
#define L_TOT 25376        // 101504 bytes

__global__ __launch_bounds__(256) void init_flags(float* __restrict__ ws) {
    unsigned* f = (unsigned*)(ws + FLAG_OFF);
    size_t idx = (size_t)blockIdx.x * 256 + threadIdx.x;
    if (idx < FLAG_U32S) f[idx] = 0u;
}

// Persistent LSTM: 256 WGs x 512 thr = 64 rg x 4 bgr.
// rg owns 8 units (rg*8..+8) x 4 gates = 32 gate-rows; bgr owns 16 batches.
// Row l (0..31): gate = l>>3, unit = l&7, global row = (l>>3)*512 + rg*8 + (l&7).
// Wave w: rows w*4..w*4+3. Lane L: kc = L>>3 (k-chunk), b_l = L&7 (+8 = 2nd half).
// DELTA vs R10 (6.15ms anchor): 32x16 ownership halves broadcast Whh LDS reads
// (128->64/wave/step; each w4 feeds 2 batch-halves) and halves Wih global
// loads. Everything else (hs layout, LDS h staging, flag barrier) = R10.
// Audit: w-reads 8-lane broadcast (free); h-reads 2-way bank alias (free);
// gsm stride 17 (odd, conflict-free). Wih stays global/L2 (R9's LDS-Wih was
// 8-way bank-conflicted -- 1KB row stride).
__global__ __launch_bounds__(512) void lstm_persistent(
    const float* __restrict__ Whh, const float* __restrict__ Wih,
    const float* __restrict__ bih, const float* __restrict__ bhh,
    const float* __restrict__ emb, const int* __restrict__ x,
    float* __restrict__ ws)
{
    const int wg  = blockIdx.x;
    const int rg  = wg & 63;
    const int bgr = wg >> 6;
    const int tid = threadIdx.x;
    const int w   = tid >> 6;
    const int L   = tid & 63;
    const int b_l = L & 7;
    const int kc  = L >> 3;

    float* hs = ws;
    unsigned* flags = (unsigned*)(ws + FLAG_OFF);

    extern __shared__ float smem[];
    float* whh_l = smem + L_WHH;   // [l(32)][512]
    float* h_l   = smem + L_H;     // [b(16)][520]
    float* gsm   = smem + L_GSM;   // [l(32)][17]
    float* cs_l  = smem + L_CS;    // [u(8)][16]

    int grow[4];
#pragma unroll
    for (int r = 0; r < 4; r++) {
        int l = w * 4 + r;
        grow[r] = (l >> 3) * HH + rg * 8 + (l & 7);
    }

    // ---- stage Whh slice (32 rows x 512) into LDS, coalesced ----
    for (int j = 0; j < 32; j++) {
        int idx = j * 512 + tid;          // l*512 + k
        int l = idx >> 9;
        int k = idx & 511;
        int gr = (l >> 3) * HH + rg * 8 + (l & 7);
        whh_l[idx] = Whh[(size_t)gr * HH + k];
    }

    // bias preload (activation threads: u = tid&7, bb = tid>>3, 128 threads)
    float bs0 = 0.f, bs1 = 0.f, bs2 = 0.f, bs3 = 0.f;
    if (tid < 128) {
        const int u  = tid & 7;
        const int gu = rg * 8 + u;
        bs0 = bih[0 * HH + gu] + bhh[0 * HH + gu];
        bs1 = bih[1 * HH + gu] + bhh[1 * HH + gu];
        bs2 = bih[2 * HH + gu] + bhh[2 * HH + gu];
        bs3 = bih[3 * HH + gu] + bhh[3 * HH + gu];
        cs_l[(tid & 7) * 16 + (tid >> 3)] = 0.0f;
    }

    // h_{-1} = 0 (16 rows x 520 incl. padding)
    for (int j = 0; j < 17; j++) {
        int idx = j * 512 + tid;
        if (idx < 8320) h_l[idx] = 0.0f;
    }

    // ---- ih gates for t=0: acc_ih[r*2+bh] ----
    float acc_ih[8];
#pragma unroll
    for (int i = 0; i < 8; i++) acc_ih[i] = 0.0f;
    {
        const int xv0 = x[0 * BB + bgr * 16 + b_l];
        const int xv1 = x[0 * BB + bgr * 16 + 8 + b_l];
        const float* er0 = emb + (size_t)xv0 * EE;
        const float* er1 = emb + (size_t)xv1 * EE;
        for (int c = 0; c < 8; c++) {
            const int k0 = c * 32 + kc * 4;
            float4 ea = *(const float4*)(er0 + k0);
            float4 eb = *(const float4*)(er1 + k0);
            ea.x *= 16.0f; ea.y *= 16.0f; ea.z *= 16.0f; ea.w *= 16.0f;
            eb.x *= 16.0f; eb.y *= 16.0f; eb.z *= 16.0f; eb.w *= 16.0f;
#pragma unroll
            for (int r = 0; r < 4; r++) {
                float4 w4 = *(const float4*)(Wih + (size_t)grow[r] * EE + k0);
                acc_ih[r * 2 + 0] += w4.x * ea.x + w4.y * ea.y + w4.z * ea.z + w4.w * ea.w;
                acc_ih[r * 2 + 1] += w4.x * eb.x + w4.y * eb.y + w4.z * eb.z + w4.w * eb.w;
            }
        }
    }
    __syncthreads();   // whh_l / h_l / cs_l ready

    const float* wbase = whh_l + (size_t)(w * 4) * 512;

    for (int t = 0; t < SS; t++) {
        // ---- hh gates: each w4 LDS read feeds both batch-halves ----
        float acc[8];
#pragma unroll
        for (int i = 0; i < 8; i++) acc[i] = acc_ih[i];
        const float* hra = h_l + b_l * 520;
        const float* hrb = h_l + (8 + b_l) * 520;
        for (int c = 0; c < 16; c++) {
            const int k0 = c * 32 + kc * 4;
            float4 ha = *(const float4*)(hra + k0);
            float4 hb = *(const float4*)(hrb + k0);
#pragma unroll
            for (int r = 0; r < 4; r++) {
                float4 w4 = *(const float4*)(wbase + r * 512 + k0);
                acc[r * 2 + 0] += w4.x * ha.x + w4.y * ha.y + w4.z * ha.z + w4.w * ha.w;
                acc[r * 2 + 1] += w4.x * hb.x + w4.y * hb.y + w4.z * hb.z + w4.w * hb.w;
            }
        }

        // ---- reduce over 8 kc-lanes (lane bits 3,4,5) ----
#pragma unroll
        for (int i = 0; i < 8; i++) {
            acc[i] += __shfl_xor(acc[i], 8, 64);
            acc[i] += __shfl_xor(acc[i], 16, 64);
            acc[i] += __shfl_xor(acc[i], 32, 64);
        }
        // lane kc=j writes value j: (r = j&3, bh = j>>2); static select
        float myv = acc[0];
#pragma unroll
        for (int j = 1; j < 8; j++)
            if (kc == j) myv = acc[(j & 3) * 2 + (j >> 2)];
        gsm[(w * 4 + (kc & 3)) * 17 + (kc >> 2) * 8 + b_l] = myv;
        __syncthreads();

        // ---- activations + state update + h_t store (relaxed agent) ----
        if (tid < 128) {
            const int u  = tid & 7;
            const int bb = tid >> 3;           // 0..15
            const int gu = rg * 8 + u;
            float g0 = gsm[(0 * 8 + u) * 17 + bb] + bs0;
            float g1 = gsm[(1 * 8 + u) * 17 + bb] + bs1;
            float g2 = gsm[(2 * 8 + u) * 17 + bb] + bs2;
            float g3 = gsm[(3 * 8 + u) * 17 + bb] + bs3;
            float i_ = 1.0f / (1.0f + expf(-g0));
            float f_ = 1.0f / (1.0f + expf(-g1));
            float o_ = 1.0f / (1.0f + expf(-g3));
            const int gb = bgr * 16 + bb;
            float cn = f_ * cs_l[u * 16 + bb] + i_ * tanhf(g2);
            float hn = o_ * tanhf(cn);
            cs_l[u * 16 + bb] = cn;
            __hip_atomic_store(&hs[(size_t)t * BB * HH + (size_t)gb * HH + gu],
                               hn, __ATOMIC_RELAXED, __HIP_MEMORY_SCOPE_AGENT);
        }
        __syncthreads();   // each wave drains vmcnt before barrier: h at LLC

        if (t + 1 < SS) {
            // ---- publish our rg's flag (data already at LLC) ----
            if (tid == 0)
                __hip_atomic_store(&flags[((size_t)t * 4 + bgr) * 64 + rg], 1u,
                                   __ATOMIC_RELAXED, __HIP_MEMORY_SCOPE_AGENT);

            // ---- ih(t+1) overlapped with the wait window ----
            {
                const int xv0 = x[(t + 1) * BB + bgr * 16 + b_l];
                const int xv1 = x[(t + 1) * BB + bgr * 16 + 8 + b_l];
                const float* er0 = emb + (size_t)xv0 * EE;
                const float* er1 = emb + (size_t)xv1 * EE;
#pragma unroll
                for (int i = 0; i < 8; i++) acc_ih[i] = 0.0f;
                for (int c = 0; c < 8; c++) {
                    const int k0 = c * 32 + kc * 4;
                    float4 ea = *(const float4*)(er0 + k0);
                    float4 eb = *(const float4*)(er1 + k0);
                    ea.x *= 16.0f; ea.y *= 16.0f; ea.z *= 16.0f; ea.w *= 16.0f;
                    eb.x *= 16.0f; eb.y *= 16.0f; eb.z *= 16.0f; eb.w *= 16.0f;
#pragma unroll
                    for (int r = 0; r < 4; r++) {
                        float4 w4 = *(const float4*)(Wih + (size_t)grow[r] * EE + k0);
                        acc_ih[r * 2 + 0] += w4.x * ea.x + w4.y * ea.y + w4.z * ea.z + w4.w * ea.w;
                        acc_ih[r * 2 + 1] += w4.x * eb.x + w4.y * eb.y + w4.z * eb.z + w4.w * eb.w;
                    }
                }
            }

            // ---- ALL waves poll the 64-flag line for (t, bgr) ----
            {
                const unsigned* fl = flags + ((size_t)t * 4 + bgr) * 64;
                for (;;) {
                    unsigned v = __hip_atomic_load(&fl[L], __ATOMIC_RELAXED,
                                                   __HIP_MEMORY_SCOPE_AGENT);
                    if (__all(v != 0u)) break;
                }
            }

            // ---- stage h_t into LDS (16 batches x 512) ----
            const float* hsrc = hs + (size_t)t * BB * HH + (size_t)bgr * 16 * HH;
#pragma unroll
            for (int j = 0; j < 16; j++) {
                int idx = j * 512 + tid;
                float v = __hip_atomic_load(&hsrc[idx], __ATOMIC_RELAXED,
                                            __HIP_MEMORY_SCOPE_AGENT);
                h_l[(idx >> 9) * 520 + (idx & 511)] = v;
            }
            __syncthreads();
        }
    }
}

// one wave per (t,b): logits = h @ W_out^T + b_out, then log_softmax
__global__ __launch_bounds__(256) void emis_kernel(
    const float* __restrict__ Wout, const float* __restrict__ bout,
    float* __restrict__ ws)
{
    int wid = blockIdx.x * 4 + (threadIdx.x >> 6);  // t*64 + b
    int L   = threadIdx.x & 63;
    const float* h = ws + (size_t)wid * HH;
    float hv[8];
#pragma unroll
    for (int i = 0; i < 8; i++) hv[i] = h[i * 64 + L];
    float acc[9];
#pragma unroll
    for (int tg = 0; tg < 9; tg++) acc[tg] = 0.0f;
    for (int i = 0; i < 8; i++) {
#pragma unroll
        for (int tg = 0; tg < 9; tg++)
            acc[tg] += Wout[tg * HH + i * 64 + L] * hv[i];
    }
#pragma unroll
    for (int tg = 0; tg < 9; tg++) {
        acc[tg] += __shfl_xor(acc[tg], 1, 64);
        acc[tg] += __shfl_xor(acc[tg], 2, 64);
        acc[tg] += __shfl_xor(acc[tg], 4, 64);
        acc[tg] += __shfl_xor(acc[tg], 8, 64);
        acc[tg] += __shfl_xor(acc[tg], 16, 64);
        acc[tg] += __shfl_xor(acc[tg], 32, 64);
    }
    float lg[9];
#pragma unroll
    for (int tg = 0; tg < 9; tg++) lg[tg] = acc[tg] + bout[tg];
    float m = lg[0];
#pragma unroll
    for (int tg = 1; tg < 9; tg++) m = fmaxf(m, lg[tg]);
    float ssum = 0.0f;
#pragma unroll
    for (int tg = 0; tg < 9; tg++) ssum += expf(lg[tg] - m);
    float lse = m + logf(ssum);
    float myo = lg[0] - lse;
#pragma unroll
    for (int tg = 1; tg < 9; tg++) if (L == tg) myo = lg[tg] - lse;
    if (L < 9) ws[EM_OFF + (size_t)wid * 9 + L] = myo;
}

// merged CRF: blocks 0..7 numerator, 8..15 forward(logZ), 16..23 viterbi
__global__ __launch_bounds__(512) void crf_all(
    const int* __restrict__ x, const int* __restrict__ bio,
    const float* __restrict__ start_t, const float* __restrict__ end_t,
    const float* __restrict__ trans, float* __restrict__ ws,
    float* __restrict__ out)
{
    const float* em = ws + EM_OFF;
    const int role  = blockIdx.x >> 3;
    const int local = blockIdx.x & 7;
    const int tid   = threadIdx.x;

    __shared__ float sc[9][8];
    __shared__ unsigned char hist[SS - 1][8][9];

    if (role == 0) {
        int b = local * 8 + (tid >> 6);
        int L = tid & 63;
        float sum = 0.0f;
        int cntm = 0;
#pragma unroll
        for (int j = 0; j < 8; j++) {
            int s = j * 64 + L;
            int tg = bio[s * BB + b];
            bool mk = (x[s * BB + b] != 0);
            cntm += mk ? 1 : 0;
            if (s == 0) {
                sum += start_t[tg] + em[(size_t)b * 9 + tg];
            } else if (mk) {
                int tp = bio[(s - 1) * BB + b];
                sum += em[((size_t)s * BB + b) * 9 + tg] + trans[tp * 9 + tg];
            }
        }
#pragma unroll
        for (int d = 1; d < 64; d <<= 1) {
            sum += __shfl_xor(sum, d, 64);
            cntm += __shfl_xor(cntm, d, 64);
        }
        if (L == 0) {
            int se = cntm - 1;
            sum += end_t[bio[se * BB + b]];
            ws[NUM_OFF + b] = sum;
        }
        return;
    }

    const int b_l = tid & 7;
    const int j   = tid >> 3;          // active j < 9
    const int b   = local * 8 + b_l;
    float tc[9];
    if (j < 9) {
#pragma unroll
        for (int i = 0; i < 9; i++) tc[i] = trans[i * 9 + j];
        sc[j][b_l] = start_t[j] + em[(size_t)b * 9 + j];
    }
    __syncthreads();

    if (role == 1) {
        for (int s = 1; s < SS; s++) {
            float nv = 0.0f;
            if (j < 9) {
                float sv[9];
                float m = -3.4e38f;
#pragma unroll
                for (int i = 0; i < 9; i++) {
                    sv[i] = sc[i][b_l] + tc[i];
                    m = fmaxf(m, sv[i]);
                }
                float ssum = 0.0f;
#pragma unroll
                for (int i = 0; i < 9; i++) ssum += expf(sv[i] - m);
                nv = m + logf(ssum) + em[((size_t)s * BB + b) * 9 + j];
            }
            bool mk = (x[s * BB + b] != 0);
            __syncthreads();
            if (j < 9 && mk) sc[j][b_l] = nv;
            __syncthreads();
        }
        if (j == 0) {
            float m = -3.4e38f;
#pragma unroll
            for (int i = 0; i < 9; i++) m = fmaxf(m, sc[i][b_l] + end_t[i]);
            float ssum = 0.0f;
#pragma unroll
            for (int i = 0; i < 9; i++) ssum += expf(sc[i][b_l] + end_t[i] - m);
            ws[NORM_OFF + b] = m + logf(ssum);
        }
    } else {
        for (int s = 1; s < SS; s++) {
            float nv = 0.0f;
            if (j < 9) {
                float best = sc[0][b_l] + tc[0];
                int bi = 0;
#pragma unroll
                for (int i = 1; i < 9; i++) {
                    float v = sc[i][b_l] + tc[i];
                    if (v > best) { best = v; bi = i; }  // first-max = jnp.argmax
                }
                hist[s - 1][b_l][j] = (unsigned char)bi;
                nv = best + em[((size_t)s * BB + b) * 9 + j];
            }
            __syncthreads();
            if (j < 9) sc[j][b_l] = nv;
            __syncthreads();
        }
        if (tid < 8) {
            int bl = tid;
            int gb = local * 8 + bl;
            float best = sc[0][bl] + end_t[0];
            int cur = 0;
#pragma unroll
            for (int i = 1; i < 9; i++) {
                float v = sc[i][bl] + end_t[i];
                if (v > best) { best = v; cur = i; }
            }
            out[1 + (size_t)(SS - 1) * BB + gb] = (float)cur;
            for (int s = SS - 2; s >= 0; s--) {
                cur = hist[s][bl][cur];
                out[1 + (size_t)s * BB + gb] = (float)cur;
            }
        }
    }
}

__global__ __launch_bounds__(64) void final_llh(const float* __restrict__ ws,
                                               float* __restrict__ out)
{
    int L = threadIdx.x;
    float v = ws[NUM_OFF + L] - ws[NORM_OFF + L];
    v += __shfl_xor(v, 1, 64);
    v += __shfl_xor(v, 2, 64);
    v += __shfl_xor(v, 4, 64);
    v += __shfl_xor(v, 8, 64);
    v += __shfl_xor(v, 16, 64);
    v += __shfl_xor(v, 32, 64);
    if (L == 0) out[0] = -v;
}

extern "C" void kernel_launch(void* const* d_in, const int* in_sizes, int n_in,
                              void* d_out, int out_size, void* d_ws, size_t ws_size,
                              hipStream_t stream) {
    const int*   x       = (const int*)d_in[0];
    const int*   bio     = (const int*)d_in[1];
    const float* emb     = (const float*)d_in[2];
    const float* W_ih    = (const float*)d_in[3];
    const float* W_hh    = (const float*)d_in[4];
    const float* b_ih    = (const float*)d_in[5];
    const float* b_hh    = (const float*)d_in[6];
    const float* W_out   = (const float*)d_in[7];
    const float* b_out   = (const float*)d_in[8];
    const float* start_t = (const float*)d_in[9];
    const float* end_t   = (const float*)d_in[10];
    const float* trans   = (const float*)d_in[11];
    float* out = (float*)d_out;
    float* ws  = (float*)d_ws;

    const size_t dyn_lds = (size_t)L_TOT * sizeof(float);   // 101504 B
    hipFuncSetAttribute((const void*)lstm_persistent,
                        hipFuncAttributeMaxDynamicSharedMemorySize,
                        (int)dyn_lds);

    init_flags<<<512, 256, 0, stream>>>(ws);
    lstm_persistent<<<NWG, 512, dyn_lds, stream>>>(W_hh, W_ih, b_ih, b_hh, emb, x, ws);
    emis_kernel<<<SS * BB / 4, 256, 0, stream>>>(W_out, b_out, ws);
    crf_all<<<24, 512, 0, stream>>>(x, bio, start_t, end_t, trans, ws, out);
    final_llh<<<1, 64, 0, stream>>>(ws, out);
}